// Round 1
// baseline (222.065 us; speedup 1.0000x reference)
//
#include <hip/hip_runtime.h>

#define T_SEQ 4096
#define DMODEL 1024
#define NHEAD 16
#define HDIM 64
#define WIN 128

typedef __attribute__((ext_vector_type(8))) short bf16x8;
typedef __attribute__((ext_vector_type(4))) float f32x4;
typedef __attribute__((ext_vector_type(4))) unsigned short u16x4;

__device__ __forceinline__ unsigned short f2bf(float f) {
  unsigned int u = __builtin_bit_cast(unsigned int, f);
  return (unsigned short)((u + 0x7fffu + ((u >> 16) & 1u)) >> 16);
}

// ---------------- fp32 -> bf16 convert ----------------
__global__ void convert_f32_bf16(const float* __restrict__ src,
                                 unsigned short* __restrict__ dst, int n4) {
  int stride = gridDim.x * blockDim.x;
  for (int i = blockIdx.x * blockDim.x + threadIdx.x; i < n4; i += stride) {
    float4 v = reinterpret_cast<const float4*>(src)[i];
    u16x4 o;
    o.x = f2bf(v.x); o.y = f2bf(v.y); o.z = f2bf(v.z); o.w = f2bf(v.w);
    reinterpret_cast<u16x4*>(dst)[i] = o;
  }
}

// ---------------- GEMM  C[t][e] = sum_k A[t][k] * B[e][k]  (B^T layout) ----
// EPI 0: qkv epilogue (+b_in, scatter to q/k/vt bf16 buffers)
// EPI 1: out epilogue (+b_out, +x residual, fp32 store)
template <int EPI>
__global__ __launch_bounds__(256) void gemm_bt(
    const unsigned short* __restrict__ A,
    const unsigned short* __restrict__ B,
    const float* __restrict__ bias,
    unsigned short* __restrict__ q_buf,
    unsigned short* __restrict__ k_buf,
    unsigned short* __restrict__ vt_buf,
    const float* __restrict__ x_res,
    float* __restrict__ out) {
  const int K = DMODEL;
  int lane = threadIdx.x & 63;
  int wave = threadIdx.x >> 6;
  int wr = wave >> 1, wc = wave & 1;
  int lo = lane & 15, hi = lane >> 4;
  int t0 = blockIdx.y * 128 + wr * 64;
  int e0 = blockIdx.x * 128 + wc * 64;

  f32x4 acc[4][4];
#pragma unroll
  for (int m = 0; m < 4; ++m)
#pragma unroll
    for (int n = 0; n < 4; ++n) acc[m][n] = (f32x4){0.f, 0.f, 0.f, 0.f};

  const unsigned short* Ab = A + (size_t)(t0 + lo) * K + hi * 8;
  const unsigned short* Bb = B + (size_t)(e0 + lo) * K + hi * 8;

  for (int k0 = 0; k0 < K; k0 += 32) {
    bf16x8 af[4], bfr[4];
#pragma unroll
    for (int m = 0; m < 4; ++m)
      af[m] = *reinterpret_cast<const bf16x8*>(Ab + (size_t)m * 16 * K + k0);
#pragma unroll
    for (int n = 0; n < 4; ++n)
      bfr[n] = *reinterpret_cast<const bf16x8*>(Bb + (size_t)n * 16 * K + k0);
#pragma unroll
    for (int m = 0; m < 4; ++m)
#pragma unroll
      for (int n = 0; n < 4; ++n)
        acc[m][n] =
            __builtin_amdgcn_mfma_f32_16x16x32_bf16(af[m], bfr[n], acc[m][n], 0, 0, 0);
  }

#pragma unroll
  for (int m = 0; m < 4; ++m) {
#pragma unroll
    for (int n = 0; n < 4; ++n) {
      int e = e0 + n * 16 + lo;
      float bv = bias[e];
#pragma unroll
      for (int j = 0; j < 4; ++j) {
        int t = t0 + m * 16 + hi * 4 + j;
        float val = acc[m][n][j] + bv;
        if (EPI == 0) {
          unsigned short bb = f2bf(val);
          int part = e >> 10;
          int h = (e >> 6) & 15;
          int d = e & 63;
          if (part == 0)
            q_buf[((size_t)h * T_SEQ + t) * HDIM + d] = bb;
          else if (part == 1)
            k_buf[((size_t)h * T_SEQ + t) * HDIM + d] = bb;
          else  // V stored transposed per head: vt[h][d][t]
            vt_buf[((size_t)(h * HDIM + d)) * T_SEQ + t] = bb;
        } else {
          size_t idx = (size_t)t * DMODEL + e;
          out[idx] = val + x_res[idx];
        }
      }
    }
  }
}

// ---------------- windowed flash attention ----------------
// 1 wave per (head, 16-query tile); 32-key tiles; online softmax fp32.
__global__ __launch_bounds__(64) void win_attn(
    const unsigned short* __restrict__ q_buf,
    const unsigned short* __restrict__ k_buf,
    const unsigned short* __restrict__ vt_buf,
    unsigned short* __restrict__ ctx) {
  __shared__ __align__(16) unsigned short p_lds[16 * 32];
  int lane = threadIdx.x;
  int lo = lane & 15, hi = lane >> 4;
  int h = blockIdx.x & (NHEAD - 1);
  int q0 = (blockIdx.x >> 4) * 16;
  const float scale = 0.125f;  // 1/sqrt(64)

  const unsigned short* qrow = q_buf + ((size_t)h * T_SEQ + q0 + lo) * HDIM + hi * 8;
  bf16x8 aq0 = *reinterpret_cast<const bf16x8*>(qrow);
  bf16x8 aq1 = *reinterpret_cast<const bf16x8*>(qrow + 32);

  float m_r[4], l_r[4];
  f32x4 o[4];
#pragma unroll
  for (int j = 0; j < 4; ++j) { m_r[j] = -1e30f; l_r[j] = 0.f; }
#pragma unroll
  for (int n = 0; n < 4; ++n) o[n] = (f32x4){0.f, 0.f, 0.f, 0.f};

  int jstart = q0 - WIN; if (jstart < 0) jstart = 0;
  int jend = q0 + 16 + WIN; if (jend > T_SEQ) jend = T_SEQ;

  for (int j0 = jstart; j0 < jend; j0 += 32) {
    // ---- S = Q K^T for 16x32 key tile ----
    f32x4 s[2];
#pragma unroll
    for (int c = 0; c < 2; ++c) {
      int krow = j0 + c * 16 + lo;
      if (krow > T_SEQ - 1) krow = T_SEQ - 1;  // clamp; masked below
      const unsigned short* kp = k_buf + ((size_t)h * T_SEQ + krow) * HDIM + hi * 8;
      bf16x8 bk0 = *reinterpret_cast<const bf16x8*>(kp);
      bf16x8 bk1 = *reinterpret_cast<const bf16x8*>(kp + 32);
      f32x4 z = (f32x4){0.f, 0.f, 0.f, 0.f};
      z = __builtin_amdgcn_mfma_f32_16x16x32_bf16(aq0, bk0, z, 0, 0, 0);
      z = __builtin_amdgcn_mfma_f32_16x16x32_bf16(aq1, bk1, z, 0, 0, 0);
      s[c] = z;
    }
    // ---- mask + scale + row stats (rows live on lane quads: row=hi*4+j) ----
    float pvv[2][4];
#pragma unroll
    for (int j = 0; j < 4; ++j) {
      int q = q0 + hi * 4 + j;
      float best = -1e30f;
#pragma unroll
      for (int c = 0; c < 2; ++c) {
        int kj = j0 + c * 16 + lo;
        bool ok = (q - kj <= WIN) && (kj - q <= WIN) && (kj < jend);
        float sv = ok ? s[c][j] * scale : -1e30f;
        pvv[c][j] = sv;
        best = fmaxf(best, sv);
      }
#pragma unroll
      for (int w = 1; w < 16; w <<= 1) best = fmaxf(best, __shfl_xor(best, w, 64));
      // online update for this row
      float mn = fmaxf(m_r[j], best);
      float alpha = __expf(m_r[j] - mn);
      m_r[j] = mn;
      float psum = 0.f;
#pragma unroll
      for (int c = 0; c < 2; ++c) {
        float p = __expf(pvv[c][j] - mn);
        pvv[c][j] = p;
        psum += p;
      }
#pragma unroll
      for (int w = 1; w < 16; w <<= 1) psum += __shfl_xor(psum, w, 64);
      l_r[j] = l_r[j] * alpha + psum;
#pragma unroll
      for (int n = 0; n < 4; ++n) o[n][j] *= alpha;
    }
    // ---- P (16x32) through LDS to A-fragment layout ----
#pragma unroll
    for (int c = 0; c < 2; ++c)
#pragma unroll
      for (int j = 0; j < 4; ++j)
        p_lds[(hi * 4 + j) * 32 + c * 16 + lo] = f2bf(pvv[c][j]);
    __syncthreads();
    bf16x8 pa = *reinterpret_cast<const bf16x8*>(&p_lds[lo * 32 + hi * 8]);
    // ---- O += P V  (V transposed: vt[h][d][t], contiguous in t) ----
#pragma unroll
    for (int n = 0; n < 4; ++n) {
      const unsigned short* vp =
          vt_buf + ((size_t)(h * HDIM + n * 16 + lo)) * T_SEQ + j0 + hi * 8;
      bf16x8 bv = *reinterpret_cast<const bf16x8*>(vp);
      o[n] = __builtin_amdgcn_mfma_f32_16x16x32_bf16(pa, bv, o[n], 0, 0, 0);
    }
    __syncthreads();
  }
  // ---- epilogue: ctx[t][h*64+d] bf16 ----
#pragma unroll
  for (int j = 0; j < 4; ++j) {
    int t = q0 + hi * 4 + j;
    float inv = 1.f / l_r[j];
#pragma unroll
    for (int n = 0; n < 4; ++n)
      ctx[(size_t)t * DMODEL + h * HDIM + n * 16 + lo] = f2bf(o[n][j] * inv);
  }
}

extern "C" void kernel_launch(void* const* d_in, const int* in_sizes, int n_in,
                              void* d_out, int out_size, void* d_ws, size_t ws_size,
                              hipStream_t stream) {
  const float* x = (const float*)d_in[0];
  const float* w_in = (const float*)d_in[1];
  const float* b_in = (const float*)d_in[2];
  const float* w_out = (const float*)d_in[3];
  const float* b_out = (const float*)d_in[4];
  float* out = (float*)d_out;

  char* ws = (char*)d_ws;
  size_t off = 0;
  auto take = [&](size_t bytes) {
    char* p = ws + off;
    off += (bytes + 255) & ~(size_t)255;
    return p;
  };
  unsigned short* x_bf = (unsigned short*)take((size_t)T_SEQ * DMODEL * 2);
  unsigned short* w_in_bf = (unsigned short*)take((size_t)3 * DMODEL * DMODEL * 2);
  unsigned short* w_out_bf = (unsigned short*)take((size_t)DMODEL * DMODEL * 2);
  unsigned short* q_buf = (unsigned short*)take((size_t)T_SEQ * DMODEL * 2);
  unsigned short* k_buf = (unsigned short*)take((size_t)T_SEQ * DMODEL * 2);
  unsigned short* vt_buf = (unsigned short*)take((size_t)T_SEQ * DMODEL * 2 + 4096);
  unsigned short* ctx = (unsigned short*)take((size_t)T_SEQ * DMODEL * 2);

  convert_f32_bf16<<<2048, 256, 0, stream>>>(x, x_bf, T_SEQ * DMODEL / 4);
  convert_f32_bf16<<<2048, 256, 0, stream>>>(w_in, w_in_bf, 3 * DMODEL * DMODEL / 4);
  convert_f32_bf16<<<1024, 256, 0, stream>>>(w_out, w_out_bf, DMODEL * DMODEL / 4);

  dim3 g1(3 * DMODEL / 128, T_SEQ / 128);  // (24, 32)
  gemm_bt<0><<<g1, 256, 0, stream>>>(x_bf, w_in_bf, b_in, q_buf, k_buf, vt_buf,
                                     nullptr, nullptr);

  win_attn<<<(T_SEQ / 16) * NHEAD, 64, 0, stream>>>(q_buf, k_buf, vt_buf, ctx);

  dim3 g2(DMODEL / 128, T_SEQ / 128);  // (8, 32)
  gemm_bt<1><<<g2, 256, 0, stream>>>(ctx, w_out_bf, b_out, nullptr, nullptr, nullptr,
                                     x, out);
}

// Round 2
// 117.415 us; speedup vs baseline: 1.8913x; 1.8913x over previous
//
#include <hip/hip_runtime.h>

#define T_SEQ 4096
#define DMODEL 1024
#define NHEAD 16
#define HDIM 64
#define WIN 128

typedef __attribute__((ext_vector_type(8))) short bf16x8;
typedef __attribute__((ext_vector_type(4))) float f32x4;
typedef __attribute__((ext_vector_type(4))) unsigned short u16x4;

__device__ __forceinline__ unsigned short f2bf(float f) {
  unsigned int u = __builtin_bit_cast(unsigned int, f);
  return (unsigned short)((u + 0x7fffu + ((u >> 16) & 1u)) >> 16);
}

__device__ __forceinline__ void gload_lds16(const unsigned short* g,
                                            unsigned short* l) {
  __builtin_amdgcn_global_load_lds(
      (const __attribute__((address_space(1))) void*)g,
      (__attribute__((address_space(3))) void*)l, 16, 0, 0);
}

// ---------------- fp32 -> bf16 convert ----------------
__global__ void convert_f32_bf16(const float* __restrict__ src,
                                 unsigned short* __restrict__ dst, int n4) {
  int stride = gridDim.x * blockDim.x;
  for (int i = blockIdx.x * blockDim.x + threadIdx.x; i < n4; i += stride) {
    float4 v = reinterpret_cast<const float4*>(src)[i];
    u16x4 o;
    o.x = f2bf(v.x); o.y = f2bf(v.y); o.z = f2bf(v.z); o.w = f2bf(v.w);
    reinterpret_cast<u16x4*>(dst)[i] = o;
  }
}

// ---------------- GEMM (m97 structure): C[t][e] = sum_k A[t][k]*B[e][k] ----
// 128x128 tile, BK=32, LDS staging via global_load_lds width=16.
// EPI 0: qkv epilogue (+b_in, scatter to q/k/vt bf16 buffers)
// EPI 1: out epilogue (+b_out, +x residual, fp32 store)
template <int EPI>
__global__ __launch_bounds__(256) void gemm_lds(
    const unsigned short* __restrict__ A,
    const unsigned short* __restrict__ B,
    const float* __restrict__ bias,
    unsigned short* __restrict__ q_buf,
    unsigned short* __restrict__ k_buf,
    unsigned short* __restrict__ vt_buf,
    const float* __restrict__ x_res,
    float* __restrict__ out) {
  const int K = DMODEL;
  __shared__ __align__(16) unsigned short As[128 * 32];  // [128][32] row-major
  __shared__ __align__(16) unsigned short Bs[128 * 32];

  int tid = threadIdx.x;
  int lane = tid & 63;
  int wave = tid >> 6;
  int wr = wave >> 1, wc = wave & 1;
  int lo = lane & 15, hi = lane >> 4;
  int t0 = blockIdx.y * 128;
  int e0 = blockIdx.x * 128;

  f32x4 acc[4][4];
#pragma unroll
  for (int m = 0; m < 4; ++m)
#pragma unroll
    for (int n = 0; n < 4; ++n) acc[m][n] = (f32x4){0.f, 0.f, 0.f, 0.f};

  // staging geometry: tile 128 rows x 32 cols bf16 = 8192B; 16B per lane.
  // linear chunk i (0..511): row = i/4, col8 = i%4. Thread covers i = l*256+tid.
  int i0 = tid;              // load 0
  int i1 = 256 + tid;        // load 1
  int r0 = i0 >> 2, c0 = (i0 & 3) * 8;
  int r1 = i1 >> 2, c1 = (i1 & 3) * 8;
  // LDS dest: wave-uniform base (byte) = l*4096 + wave*1024 -> element offset
  unsigned short* ldsA0 = As + wave * 512;
  unsigned short* ldsA1 = As + 2048 + wave * 512;
  unsigned short* ldsB0 = Bs + wave * 512;
  unsigned short* ldsB1 = Bs + 2048 + wave * 512;

  const unsigned short* Arow0 = A + (size_t)(t0 + r0) * K + c0;
  const unsigned short* Arow1 = A + (size_t)(t0 + r1) * K + c1;
  const unsigned short* Brow0 = B + (size_t)(e0 + r0) * K + c0;
  const unsigned short* Brow1 = B + (size_t)(e0 + r1) * K + c1;

  for (int k0 = 0; k0 < K; k0 += 32) {
    __syncthreads();
    gload_lds16(Arow0 + k0, ldsA0);
    gload_lds16(Arow1 + k0, ldsA1);
    gload_lds16(Brow0 + k0, ldsB0);
    gload_lds16(Brow1 + k0, ldsB1);
    __syncthreads();

    bf16x8 af[4], bfr[4];
#pragma unroll
    for (int m = 0; m < 4; ++m)
      af[m] = *reinterpret_cast<const bf16x8*>(&As[(wr * 64 + m * 16 + lo) * 32 + hi * 8]);
#pragma unroll
    for (int n = 0; n < 4; ++n)
      bfr[n] = *reinterpret_cast<const bf16x8*>(&Bs[(wc * 64 + n * 16 + lo) * 32 + hi * 8]);
#pragma unroll
    for (int m = 0; m < 4; ++m)
#pragma unroll
      for (int n = 0; n < 4; ++n)
        acc[m][n] =
            __builtin_amdgcn_mfma_f32_16x16x32_bf16(af[m], bfr[n], acc[m][n], 0, 0, 0);
  }

  int t0w = t0 + wr * 64;
  int e0w = e0 + wc * 64;
#pragma unroll
  for (int m = 0; m < 4; ++m) {
#pragma unroll
    for (int n = 0; n < 4; ++n) {
      int e = e0w + n * 16 + lo;
      float bv = bias[e];
#pragma unroll
      for (int j = 0; j < 4; ++j) {
        int t = t0w + m * 16 + hi * 4 + j;
        float val = acc[m][n][j] + bv;
        if (EPI == 0) {
          unsigned short bb = f2bf(val);
          int part = e >> 10;
          int h = (e >> 6) & 15;
          int d = e & 63;
          if (part == 0)
            q_buf[((size_t)h * T_SEQ + t) * HDIM + d] = bb;
          else if (part == 1)
            k_buf[((size_t)h * T_SEQ + t) * HDIM + d] = bb;
          else  // V stored transposed per head: vt[h][d][t]
            vt_buf[((size_t)(h * HDIM + d)) * T_SEQ + t] = bb;
        } else {
          size_t idx = (size_t)t * DMODEL + e;
          out[idx] = val + x_res[idx];
        }
      }
    }
  }
}

// ---------------- windowed flash attention ----------------
// 1 wave per (head, 16-query tile); 32-key tiles; online softmax fp32.
__global__ __launch_bounds__(64) void win_attn(
    const unsigned short* __restrict__ q_buf,
    const unsigned short* __restrict__ k_buf,
    const unsigned short* __restrict__ vt_buf,
    unsigned short* __restrict__ ctx) {
  __shared__ __align__(16) unsigned short p_lds[16 * 32];
  int lane = threadIdx.x;
  int lo = lane & 15, hi = lane >> 4;
  int h = blockIdx.x & (NHEAD - 1);
  int q0 = (blockIdx.x >> 4) * 16;
  const float scale = 0.125f;  // 1/sqrt(64)

  const unsigned short* qrow = q_buf + ((size_t)h * T_SEQ + q0 + lo) * HDIM + hi * 8;
  bf16x8 aq0 = *reinterpret_cast<const bf16x8*>(qrow);
  bf16x8 aq1 = *reinterpret_cast<const bf16x8*>(qrow + 32);

  float m_r[4], l_r[4];
  f32x4 o[4];
#pragma unroll
  for (int j = 0; j < 4; ++j) { m_r[j] = -1e30f; l_r[j] = 0.f; }
#pragma unroll
  for (int n = 0; n < 4; ++n) o[n] = (f32x4){0.f, 0.f, 0.f, 0.f};

  int jstart = q0 - WIN; if (jstart < 0) jstart = 0;
  int jend = q0 + 16 + WIN; if (jend > T_SEQ) jend = T_SEQ;

  for (int j0 = jstart; j0 < jend; j0 += 32) {
    f32x4 s[2];
#pragma unroll
    for (int c = 0; c < 2; ++c) {
      int krow = j0 + c * 16 + lo;
      if (krow > T_SEQ - 1) krow = T_SEQ - 1;  // clamp; masked below
      const unsigned short* kp = k_buf + ((size_t)h * T_SEQ + krow) * HDIM + hi * 8;
      bf16x8 bk0 = *reinterpret_cast<const bf16x8*>(kp);
      bf16x8 bk1 = *reinterpret_cast<const bf16x8*>(kp + 32);
      f32x4 z = (f32x4){0.f, 0.f, 0.f, 0.f};
      z = __builtin_amdgcn_mfma_f32_16x16x32_bf16(aq0, bk0, z, 0, 0, 0);
      z = __builtin_amdgcn_mfma_f32_16x16x32_bf16(aq1, bk1, z, 0, 0, 0);
      s[c] = z;
    }
    float pvv[2][4];
#pragma unroll
    for (int j = 0; j < 4; ++j) {
      int q = q0 + hi * 4 + j;
      float best = -1e30f;
#pragma unroll
      for (int c = 0; c < 2; ++c) {
        int kj = j0 + c * 16 + lo;
        bool ok = (q - kj <= WIN) && (kj - q <= WIN) && (kj < jend);
        float sv = ok ? s[c][j] * scale : -1e30f;
        pvv[c][j] = sv;
        best = fmaxf(best, sv);
      }
#pragma unroll
      for (int w = 1; w < 16; w <<= 1) best = fmaxf(best, __shfl_xor(best, w, 64));
      float mn = fmaxf(m_r[j], best);
      float alpha = __expf(m_r[j] - mn);
      m_r[j] = mn;
      float psum = 0.f;
#pragma unroll
      for (int c = 0; c < 2; ++c) {
        float p = __expf(pvv[c][j] - mn);
        pvv[c][j] = p;
        psum += p;
      }
#pragma unroll
      for (int w = 1; w < 16; w <<= 1) psum += __shfl_xor(psum, w, 64);
      l_r[j] = l_r[j] * alpha + psum;
#pragma unroll
      for (int n = 0; n < 4; ++n) o[n][j] *= alpha;
    }
#pragma unroll
    for (int c = 0; c < 2; ++c)
#pragma unroll
      for (int j = 0; j < 4; ++j)
        p_lds[(hi * 4 + j) * 32 + c * 16 + lo] = f2bf(pvv[c][j]);
    __syncthreads();
    bf16x8 pa = *reinterpret_cast<const bf16x8*>(&p_lds[lo * 32 + hi * 8]);
#pragma unroll
    for (int n = 0; n < 4; ++n) {
      const unsigned short* vp =
          vt_buf + ((size_t)(h * HDIM + n * 16 + lo)) * T_SEQ + j0 + hi * 8;
      bf16x8 bv = *reinterpret_cast<const bf16x8*>(vp);
      o[n] = __builtin_amdgcn_mfma_f32_16x16x32_bf16(pa, bv, o[n], 0, 0, 0);
    }
    __syncthreads();
  }
#pragma unroll
  for (int j = 0; j < 4; ++j) {
    int t = q0 + hi * 4 + j;
    float inv = 1.f / l_r[j];
#pragma unroll
    for (int n = 0; n < 4; ++n)
      ctx[(size_t)t * DMODEL + h * HDIM + n * 16 + lo] = f2bf(o[n][j] * inv);
  }
}

extern "C" void kernel_launch(void* const* d_in, const int* in_sizes, int n_in,
                              void* d_out, int out_size, void* d_ws, size_t ws_size,
                              hipStream_t stream) {
  const float* x = (const float*)d_in[0];
  const float* w_in = (const float*)d_in[1];
  const float* b_in = (const float*)d_in[2];
  const float* w_out = (const float*)d_in[3];
  const float* b_out = (const float*)d_in[4];
  float* out = (float*)d_out;

  char* ws = (char*)d_ws;
  size_t off = 0;
  auto take = [&](size_t bytes) {
    char* p = ws + off;
    off += (bytes + 255) & ~(size_t)255;
    return p;
  };
  unsigned short* x_bf = (unsigned short*)take((size_t)T_SEQ * DMODEL * 2);
  unsigned short* w_in_bf = (unsigned short*)take((size_t)3 * DMODEL * DMODEL * 2);
  unsigned short* w_out_bf = (unsigned short*)take((size_t)DMODEL * DMODEL * 2);
  unsigned short* q_buf = (unsigned short*)take((size_t)T_SEQ * DMODEL * 2);
  unsigned short* k_buf = (unsigned short*)take((size_t)T_SEQ * DMODEL * 2);
  unsigned short* vt_buf = (unsigned short*)take((size_t)T_SEQ * DMODEL * 2 + 4096);
  unsigned short* ctx = (unsigned short*)take((size_t)T_SEQ * DMODEL * 2);

  convert_f32_bf16<<<2048, 256, 0, stream>>>(x, x_bf, T_SEQ * DMODEL / 4);
  convert_f32_bf16<<<2048, 256, 0, stream>>>(w_in, w_in_bf, 3 * DMODEL * DMODEL / 4);
  convert_f32_bf16<<<1024, 256, 0, stream>>>(w_out, w_out_bf, DMODEL * DMODEL / 4);

  dim3 g1(3 * DMODEL / 128, T_SEQ / 128);  // (24, 32)
  gemm_lds<0><<<g1, 256, 0, stream>>>(x_bf, w_in_bf, b_in, q_buf, k_buf, vt_buf,
                                      nullptr, nullptr);

  win_attn<<<(T_SEQ / 16) * NHEAD, 64, 0, stream>>>(q_buf, k_buf, vt_buf, ctx);

  dim3 g2(DMODEL / 128, T_SEQ / 128);  // (8, 32)
  gemm_lds<1><<<g2, 256, 0, stream>>>(ctx, w_out_bf, b_out, nullptr, nullptr, nullptr,
                                      x, out);
}